// Round 15
// baseline (147.303 us; speedup 1.0000x reference)
//
#include <hip/hip_runtime.h>

// ParaModel_69664369541839: match = v1 @ v2^T [B,L1,L2]; masked row/col max;
// s = -max/100 masked; softmax; attention-pool p1,p2; cosine(p1,p2).
// B=128, L1=L2=256, D=768, fp32 in/out.
//
// R15: ZERO-LDS K1. 9 staged structures all ~88-93us profiled, invariant to
// bytes (R10), barriers (R12), occupancy (R14), data source (warm==cold).
// Guide common-mistake #7: LDS-staging L2-resident data is pure overhead —
// per-batch working set is 1.5MB (fits XCD L2 2.6x). MFMA A/B fragments
// (row=lane&15, k=8*(lane>>4)+j, K-contig) load DIRECTLY from row-major fp32
// global: 2 float4/lane = 16 rows x 64B aligned segments. Main loop has no
// LDS, no barriers, no staging: 16 loads -> cvt_pkrtz -> 16 MFMA per K=32.
// 512 blocks x 4 waves (64x64 tiles); TLP hides L2 latency (no lockstep).
// Epilogue + K2/K3 identical to R14.

#define B_   128
#define L_   256
#define D_   768
#define NEGV (-10000.0f)

typedef _Float16 f16x8 __attribute__((ext_vector_type(8)));
typedef __fp16   h16x2 __attribute__((ext_vector_type(2)));
typedef float    f32x4 __attribute__((ext_vector_type(4)));

#define BT   128          // block tile rows == cols
#define NKT  (D_ / 32)    // 24 K-steps of 32

__device__ __forceinline__ unsigned fmap(float f) {
    unsigned u = __float_as_uint(f);
    return (u & 0x80000000u) ? ~u : (u | 0x80000000u);   // monotone float->uint
}
__device__ __forceinline__ float fdecode(unsigned u) {
    return __uint_as_float((u & 0x80000000u) ? (u ^ 0x80000000u) : ~u);
}
__device__ __forceinline__ float wred_max(float v) {
    #pragma unroll
    for (int o = 32; o; o >>= 1) v = fmaxf(v, __shfl_xor(v, o));
    return v;
}
__device__ __forceinline__ float wred_sum(float v) {
    #pragma unroll
    for (int o = 32; o; o >>= 1) v += __shfl_xor(v, o);
    return v;
}
__device__ __forceinline__ f16x8 cvt8(float4 a, float4 b) {
    union { h16x2 h2[4]; f16x8 h8; } u;
    u.h2[0] = __builtin_amdgcn_cvt_pkrtz(a.x, a.y);
    u.h2[1] = __builtin_amdgcn_cvt_pkrtz(a.z, a.w);
    u.h2[2] = __builtin_amdgcn_cvt_pkrtz(b.x, b.y);
    u.h2[3] = __builtin_amdgcn_cvt_pkrtz(b.z, b.w);
    return u.h8;
}

// K1: per (b, ti, tj): 128x128 tile, 4 waves of 64x64, operands direct from global.
// Row-max partial -> rmax_p[b][tj][row]; col-max partial -> cmax_p[b][ti][col].
__global__ __launch_bounds__(256, 3)
void k_match(const float* __restrict__ v1, const float* __restrict__ m1,
             const float* __restrict__ v2, const float* __restrict__ m2,
             float* __restrict__ rmax_p, float* __restrict__ cmax_p)
{
    __shared__ unsigned rU[BT], cU[BT];
    __shared__ float m1s[BT], m2s[BT];

    // bijective XCD swizzle: 512 blocks, 64/XCD; a batch's 4 blocks on one XCD
    const int bid = blockIdx.x;
    const int wg  = (bid & 7) * 64 + (bid >> 3);
    const int b = wg >> 2, ti = (wg >> 1) & 1, tj = wg & 1;

    const int t = threadIdx.x;
    const int lane = t & 63, w = t >> 6;      // 4 waves
    const int wr = w >> 1, wc = w & 1;        // wave tile: 64 rows x 64 cols
    const int fr = lane & 15, fg = lane >> 4;

    if (t < BT) {
        rU[t] = 0u; cU[t] = 0u;               // 0 == -inf under fmap
        m1s[t] = m1[b * L_ + ti * BT + t];
        m2s[t] = m2[b * L_ + tj * BT + t];
    }
    __syncthreads();                          // the only pre-epilogue barrier

    // fragment bases: lane reads row (base + i*16 + fr), k = kt*32 + fg*8 .. +8
    const float* pa = v1 + ((size_t)b * L_ + ti * BT + wr * 64 + fr) * D_ + fg * 8;
    const float* pb = v2 + ((size_t)b * L_ + tj * BT + wc * 64 + fr) * D_ + fg * 8;

    f32x4 acc[4][4] = {};
    for (int kt = 0; kt < NKT; ++kt) {
        const float* A_ = pa + kt * 32;
        const float* C_ = pb + kt * 32;
        float4 xa[4], ya[4], xb[4], yb[4];
        #pragma unroll
        for (int i = 0; i < 4; ++i) {         // issue all 16 loads first
            const float* r = A_ + (size_t)(i * 16) * D_;
            xa[i] = *(const float4*)r;  ya[i] = *(const float4*)(r + 4);
        }
        #pragma unroll
        for (int j = 0; j < 4; ++j) {
            const float* r = C_ + (size_t)(j * 16) * D_;
            xb[j] = *(const float4*)r;  yb[j] = *(const float4*)(r + 4);
        }
        f16x8 af[4], bf[4];
        #pragma unroll
        for (int i = 0; i < 4; ++i) af[i] = cvt8(xa[i], ya[i]);
        #pragma unroll
        for (int j = 0; j < 4; ++j) bf[j] = cvt8(xb[j], yb[j]);
        #pragma unroll
        for (int i = 0; i < 4; ++i)
            #pragma unroll
            for (int j = 0; j < 4; ++j)
                acc[i][j] = __builtin_amdgcn_mfma_f32_16x16x32_f16(af[i], bf[j], acc[i][j], 0, 0, 0);
    }

    // masked row/col max (C/D: row = wr*64 + i*16 + fg*4 + r, col = wc*64 + j*16 + fr)
    #pragma unroll
    for (int i = 0; i < 4; ++i)
        #pragma unroll
        for (int r = 0; r < 4; ++r) {
            int row = wr * 64 + i * 16 + fg * 4 + r;
            bool rv = m1s[row] > 0.f;
            float mx = NEGV;
            #pragma unroll
            for (int j = 0; j < 4; ++j) {
                int col = wc * 64 + j * 16 + fr;
                float vv = (rv && m2s[col] > 0.f) ? acc[i][j][r] : NEGV;
                mx = fmaxf(mx, vv);
            }
            atomicMax(&rU[row], fmap(mx));    // LDS-local only
        }
    #pragma unroll
    for (int j = 0; j < 4; ++j) {
        int col = wc * 64 + j * 16 + fr;
        bool cv = m2s[col] > 0.f;
        float mx = NEGV;
        #pragma unroll
        for (int i = 0; i < 4; ++i)
            #pragma unroll
            for (int r = 0; r < 4; ++r) {
                int row = wr * 64 + i * 16 + fg * 4 + r;
                float vv = (cv && m1s[row] > 0.f) ? acc[i][j][r] : NEGV;
                mx = fmaxf(mx, vv);
            }
        atomicMax(&cU[col], fmap(mx));        // LDS-local only
    }
    __syncthreads();

    // partial maxes, plain stores (each slot written by exactly one block)
    if (t < BT)
        rmax_p[((size_t)b * 2 + tj) * L_ + ti * BT + t] = fdecode(rU[t]);
    else if (t < 2 * BT)
        cmax_p[((size_t)b * 2 + ti) * L_ + tj * BT + (t - BT)] = fdecode(cU[t - BT]);
}

// K2: per (b, side, chunk): combine 2 partials -> softmax over 256 logits
// (redundant per chunk, cheap) + pool of 256 dims. 768 blocks.
__global__ __launch_bounds__(256)
void k_attn_pool(const float* __restrict__ v1, const float* __restrict__ m1,
                 const float* __restrict__ v2, const float* __restrict__ m2,
                 const float* __restrict__ rmax_p, const float* __restrict__ cmax_p,
                 float* __restrict__ pout)
{
    // XCD swizzle: 768 blocks -> 96/XCD -> consecutive batches per XCD
    const int lin = (int)blockIdx.x;
    const int swz = (lin & 7) * 96 + (lin >> 3);
    const int b = swz / 6, rem = swz % 6, side = rem / 3, chunk = rem % 3;

    const float* v  = side ? v2 : v1;
    const float* mk = side ? m2 : m1;
    const float* P  = side ? cmax_p : rmax_p;
    const int t = threadIdx.x, lane = t & 63, w = t >> 6;

    __shared__ float attn[L_];
    __shared__ float sred[4];

    float mkv = mk[b * L_ + t];
    float mxv = fmaxf(P[((size_t)b * 2 + 0) * L_ + t],
                      P[((size_t)b * 2 + 1) * L_ + t]);
    float s = (mkv > 0.f) ? (-mxv * 0.01f) : NEGV;

    float wm = wred_max(s);
    if (lane == 0) sred[w] = wm;
    __syncthreads();
    float mx = fmaxf(fmaxf(sred[0], sred[1]), fmaxf(sred[2], sred[3]));
    float e = expf(s - mx);
    __syncthreads();
    float ws = wred_sum(e);
    if (lane == 0) sred[w] = ws;
    __syncthreads();
    float sum = sred[0] + sred[1] + sred[2] + sred[3];
    attn[t] = e / sum;
    __syncthreads();

    const int d = chunk * 256 + t;
    const float* vb = v + (size_t)b * L_ * D_ + d;
    float p = 0.f;
    #pragma unroll 8
    for (int l = 0; l < L_; ++l) p += attn[l] * vb[(size_t)l * D_];
    pout[((size_t)b * 2 + side) * D_ + d] = p;
}

// K3: per batch: cosine similarity of p1, p2.
__global__ __launch_bounds__(256)
void k_cos(const float* __restrict__ pout, float* __restrict__ out)
{
    const int b = blockIdx.x, t = threadIdx.x, lane = t & 63, w = t >> 6;
    const float* p1 = pout + (size_t)b * 2 * D_;
    const float* p2 = p1 + D_;
    float dot = 0.f, n1 = 0.f, n2 = 0.f;
    for (int d = t; d < D_; d += 256) {
        float a = p1[d], c = p2[d];
        dot += a * c; n1 += a * a; n2 += c * c;
    }
    dot = wred_sum(dot); n1 = wred_sum(n1); n2 = wred_sum(n2);
    __shared__ float sd[4], sa[4], sc[4];
    if (lane == 0) { sd[w] = dot; sa[w] = n1; sc[w] = n2; }
    __syncthreads();
    if (t == 0) {
        float dd = sd[0] + sd[1] + sd[2] + sd[3];
        float aa = sa[0] + sa[1] + sa[2] + sa[3];
        float cc = sc[0] + sc[1] + sc[2] + sc[3];
        out[b] = dd / (fmaxf(sqrtf(aa), 1e-8f) * fmaxf(sqrtf(cc), 1e-8f));
    }
}

extern "C" void kernel_launch(void* const* d_in, const int* in_sizes, int n_in,
                              void* d_out, int out_size, void* d_ws, size_t ws_size,
                              hipStream_t stream)
{
    const float* v1 = (const float*)d_in[0];
    const float* m1 = (const float*)d_in[1];
    const float* v2 = (const float*)d_in[2];
    const float* m2 = (const float*)d_in[3];
    float* out = (float*)d_out;

    float* rmax_p = (float*)d_ws;                       // [B][2][256] row-max partials
    float* cmax_p = rmax_p + (size_t)B_ * 2 * L_;       // [B][2][256] col-max partials
    float* pout   = cmax_p + (size_t)B_ * 2 * L_;       // [B][2][768] pooled vectors

    k_match<<<dim3(4 * B_), 256, 0, stream>>>(v1, m1, v2, m2, rmax_p, cmax_p);

    k_attn_pool<<<dim3(B_ * 2 * 3), 256, 0, stream>>>(v1, m1, v2, m2, rmax_p, cmax_p, pout);

    k_cos<<<B_, 256, 0, stream>>>(pout, out);
}

// Round 16
// 72.327 us; speedup vs baseline: 2.0366x; 2.0366x over previous
//
#include <hip/hip_runtime.h>

// ParaModel_69664369541839: match = v1 @ v2^T [B,L1,L2]; masked row/col max;
// s = -max/100 masked; softmax; attention-pool p1,p2; cosine(p1,p2).
// B=128, L1=L2=256, D=768, fp32 in/out.
//
// R16 = R14 + LENGTH SKIPPING (work reduction, not structure). R15 proved the
// staged-LDS K1 structure is at its optimum (zero-LDS = 2x worse); ten
// structural variants bracket ~48us timed. The masks are prefix masks with
// len in [128,256] (mean 192): sub-tiles beyond len1/len2 are NEVER observably
// read (epilogue masks them; K2's attn underflows to exact 0). Skip their
// staging, ds_reads and MFMAs (E[MFMA] 56%, E[bytes] 75%); bound K2's pool at
// nlen. Lengths via __ballot popcount of the already-loaded mask slices; all
// guards wave-uniform. Grid 512 @ 2 blocks/CU lets fast blocks free CUs
// (grid 256 would realize nothing). rU/cU init = fmap(NEG) so skipped slots
// publish NEG, not NaN.

#define B_   128
#define L_   256
#define D_   768
#define NEGV (-10000.0f)
#define NEGU 0x39E3BFFFu   // fmap(-10000.0f)

typedef _Float16 f16x8 __attribute__((ext_vector_type(8)));
typedef __fp16   h16x2 __attribute__((ext_vector_type(2)));
typedef float    f32x4 __attribute__((ext_vector_type(4)));

#define BT   128          // tile rows == cols
#define BKF  64           // fp32 k-elems per staged tile (2 MFMA K-steps)
#define NKT  (D_ / BKF)   // 12
#define LDH  72           // halves per LDS row (144B: uniform bank spread)

__device__ __forceinline__ unsigned fmap(float f) {
    unsigned u = __float_as_uint(f);
    return (u & 0x80000000u) ? ~u : (u | 0x80000000u);   // monotone float->uint
}
__device__ __forceinline__ float fdecode(unsigned u) {
    return __uint_as_float((u & 0x80000000u) ? (u ^ 0x80000000u) : ~u);
}
__device__ __forceinline__ float wred_max(float v) {
    #pragma unroll
    for (int o = 32; o; o >>= 1) v = fmaxf(v, __shfl_xor(v, o));
    return v;
}
__device__ __forceinline__ float wred_sum(float v) {
    #pragma unroll
    for (int o = 32; o; o >>= 1) v += __shfl_xor(v, o);
    return v;
}
__device__ __forceinline__ f16x8 cvt8(float4 a, float4 b) {
    union { h16x2 h2[4]; f16x8 h8; } u;
    u.h2[0] = __builtin_amdgcn_cvt_pkrtz(a.x, a.y);
    u.h2[1] = __builtin_amdgcn_cvt_pkrtz(a.z, a.w);
    u.h2[2] = __builtin_amdgcn_cvt_pkrtz(b.x, b.y);
    u.h2[3] = __builtin_amdgcn_cvt_pkrtz(b.z, b.w);
    return u.h8;
}

// K1: per (b, ti, tj): 128x128 match tile via fp16 MFMA (8 waves of 32x64).
// Row-max partial -> rmax_p[b][tj][row]; col partial -> cmax_p[b][ti][col].
__global__ __launch_bounds__(512, 4)
void k_match(const float* __restrict__ v1, const float* __restrict__ m1,
             const float* __restrict__ v2, const float* __restrict__ m2,
             float* __restrict__ rmax_p, float* __restrict__ cmax_p)
{
    __shared__ __align__(16) _Float16 As[2][BT * LDH];   // 2 x 18.4 KB
    __shared__ __align__(16) _Float16 Bs[2][BT * LDH];   // 2 x 18.4 KB
    __shared__ unsigned rU[BT], cU[BT];
    __shared__ float m1s[BT], m2s[BT];
    __shared__ int sl1, sl2;

    // bijective XCD swizzle: 512 blocks, 64/XCD; a batch's 4 blocks on one XCD
    const int bid = blockIdx.x;
    const int wg  = (bid & 7) * 64 + (bid >> 3);
    const int b = wg >> 2, ti = (wg >> 1) & 1, tj = wg & 1;

    const int t = threadIdx.x;
    const int lane = t & 63, w = t >> 6;      // 8 waves
    const int wr = w >> 1, wc = w & 1;        // wave tile: 32 rows x 64 cols
    const int fr = lane & 15, fg = lane >> 4;

    if (t < BT) {
        rU[t] = NEGU; cU[t] = NEGU;           // skipped slots publish NEG
        m1s[t] = m1[b * L_ + ti * BT + t];
        m2s[t] = m2[b * L_ + tj * BT + t];
    }
    if (t == 0) { sl1 = 0; sl2 = 0; }
    __syncthreads();

    // block-local valid row/col counts (masks are prefix masks)
    unsigned long long b1 = __ballot(t < BT && m1s[t] > 0.f);
    unsigned long long b2 = __ballot(t < BT && m2s[t] > 0.f);
    if (lane == 0 && b1) atomicAdd(&sl1, (int)__popcll(b1));
    if (lane == 0 && b2) atomicAdd(&sl2, (int)__popcll(b2));
    __syncthreads();
    const int len1b = sl1, len2b = sl2;       // valid v1-rows / v2-rows in tile

    f32x4 acc[2][4] = {};

    if (len1b > 0 && len2b > 0) {
        // staging (512 thr): each operand tile 128x64 f32 -> thread owns row
        // t>>2, fp32 cols (t&3)*16..+16 (4 float4 per operand).
        const int s_r = t >> 2, s_c = (t & 3) * 16;
        const bool pA = s_r < len1b;
        const bool pB = s_r < len2b;
        const float* ga = v1 + ((size_t)b * L_ + ti * BT + s_r) * D_ + s_c;
        const float* gb = v2 + ((size_t)b * L_ + tj * BT + s_r) * D_ + s_c;

        float4 ra[4], rb[4];

        #define GLOAD(kt) do {                                                    \
            const float* A_ = ga + (kt) * BKF;                                    \
            const float* C_ = gb + (kt) * BKF;                                    \
            if (pA) {                                                             \
                ra[0] = *(const float4*)(A_);      ra[1] = *(const float4*)(A_ + 4);  \
                ra[2] = *(const float4*)(A_ + 8);  ra[3] = *(const float4*)(A_ + 12); \
            }                                                                     \
            if (pB) {                                                             \
                rb[0] = *(const float4*)(C_);      rb[1] = *(const float4*)(C_ + 4);  \
                rb[2] = *(const float4*)(C_ + 8);  rb[3] = *(const float4*)(C_ + 12); \
            }                                                                     \
        } while (0)

        #define DSWRITE(buf) do {                                                 \
            if (pA) {                                                             \
                _Float16* da = &As[buf][s_r * LDH + s_c];                         \
                *(f16x8*)da       = cvt8(ra[0], ra[1]);                           \
                *(f16x8*)(da + 8) = cvt8(ra[2], ra[3]);                           \
            }                                                                     \
            if (pB) {                                                             \
                _Float16* db = &Bs[buf][s_r * LDH + s_c];                         \
                *(f16x8*)db       = cvt8(rb[0], rb[1]);                           \
                *(f16x8*)(db + 8) = cvt8(rb[2], rb[3]);                           \
            }                                                                     \
        } while (0)

        // wave-uniform sub-tile validity
        const bool vi0 = (wr * 32      ) < len1b;
        const bool vi1 = (wr * 32 + 16 ) < len1b;
        const bool vj0 = (wc * 64      ) < len2b;
        const bool vj1 = (wc * 64 + 16 ) < len2b;
        const bool vj2 = (wc * 64 + 32 ) < len2b;
        const bool vj3 = (wc * 64 + 48 ) < len2b;

        GLOAD(0);
        DSWRITE(0);
        __syncthreads();
        int cur = 0;
        for (int kt = 0; kt < NKT; ++kt) {
            if (kt + 1 < NKT) GLOAD(kt + 1);      // issue next tile's loads early
            __builtin_amdgcn_sched_barrier(0);    // pin issue above the MFMA phase
            #pragma unroll
            for (int ks = 0; ks < 2; ++ks) {
                f16x8 af[2], bf[4];
                if (vi0) af[0] = *(const f16x8*)&As[cur][(wr * 32      + fr) * LDH + ks * 32 + fg * 8];
                if (vi1) af[1] = *(const f16x8*)&As[cur][(wr * 32 + 16 + fr) * LDH + ks * 32 + fg * 8];
                if (vj0) bf[0] = *(const f16x8*)&Bs[cur][(wc * 64      + fr) * LDH + ks * 32 + fg * 8];
                if (vj1) bf[1] = *(const f16x8*)&Bs[cur][(wc * 64 + 16 + fr) * LDH + ks * 32 + fg * 8];
                if (vj2) bf[2] = *(const f16x8*)&Bs[cur][(wc * 64 + 32 + fr) * LDH + ks * 32 + fg * 8];
                if (vj3) bf[3] = *(const f16x8*)&Bs[cur][(wc * 64 + 48 + fr) * LDH + ks * 32 + fg * 8];
                if (vi0) {
                    if (vj0) acc[0][0] = __builtin_amdgcn_mfma_f32_16x16x32_f16(af[0], bf[0], acc[0][0], 0, 0, 0);
                    if (vj1) acc[0][1] = __builtin_amdgcn_mfma_f32_16x16x32_f16(af[0], bf[1], acc[0][1], 0, 0, 0);
                    if (vj2) acc[0][2] = __builtin_amdgcn_mfma_f32_16x16x32_f16(af[0], bf[2], acc[0][2], 0, 0, 0);
                    if (vj3) acc[0][3] = __builtin_amdgcn_mfma_f32_16x16x32_f16(af[0], bf[3], acc[0][3], 0, 0, 0);
                }
                if (vi1) {
                    if (vj0) acc[1][0] = __builtin_amdgcn_mfma_f32_16x16x32_f16(af[1], bf[0], acc[1][0], 0, 0, 0);
                    if (vj1) acc[1][1] = __builtin_amdgcn_mfma_f32_16x16x32_f16(af[1], bf[1], acc[1][1], 0, 0, 0);
                    if (vj2) acc[1][2] = __builtin_amdgcn_mfma_f32_16x16x32_f16(af[1], bf[2], acc[1][2], 0, 0, 0);
                    if (vj3) acc[1][3] = __builtin_amdgcn_mfma_f32_16x16x32_f16(af[1], bf[3], acc[1][3], 0, 0, 0);
                }
            }
            __builtin_amdgcn_sched_barrier(0);    // cvt/ds_write stay after MFMAs
            if (kt + 1 < NKT) DSWRITE(cur ^ 1);
            __syncthreads();
            cur ^= 1;
        }
        #undef GLOAD
        #undef DSWRITE
    }

    // masked row/col max (C/D: row = wr*32 + i*16 + fg*4 + r, col = wc*64 + j*16 + fr)
    // acc for skipped sub-tiles is zero-init; masks guarantee those slots -> NEG.
    #pragma unroll
    for (int i = 0; i < 2; ++i)
        #pragma unroll
        for (int r = 0; r < 4; ++r) {
            int row = wr * 32 + i * 16 + fg * 4 + r;
            bool rv = m1s[row] > 0.f;
            float mx = NEGV;
            #pragma unroll
            for (int j = 0; j < 4; ++j) {
                int col = wc * 64 + j * 16 + fr;
                float vv = (rv && m2s[col] > 0.f) ? acc[i][j][r] : NEGV;
                mx = fmaxf(mx, vv);
            }
            atomicMax(&rU[row], fmap(mx));    // LDS-local only
        }
    #pragma unroll
    for (int j = 0; j < 4; ++j) {
        int col = wc * 64 + j * 16 + fr;
        bool cv = m2s[col] > 0.f;
        float mx = NEGV;
        #pragma unroll
        for (int i = 0; i < 2; ++i)
            #pragma unroll
            for (int r = 0; r < 4; ++r) {
                int row = wr * 32 + i * 16 + fg * 4 + r;
                float vv = (cv && m1s[row] > 0.f) ? acc[i][j][r] : NEGV;
                mx = fmaxf(mx, vv);
            }
        atomicMax(&cU[col], fmap(mx));        // LDS-local only
    }
    __syncthreads();

    // partial maxes, plain stores (each slot written by exactly one block)
    if (t < BT)
        rmax_p[((size_t)b * 2 + tj) * L_ + ti * BT + t] = fdecode(rU[t]);
    else if (t < 2 * BT)
        cmax_p[((size_t)b * 2 + ti) * L_ + tj * BT + (t - BT)] = fdecode(cU[t - BT]);
}

// K2: per (b, side, chunk): combine 2 partials -> softmax over 256 logits
// (redundant per chunk, cheap) + pool of nlen rows x 256 dims. 768 blocks.
__global__ __launch_bounds__(256)
void k_attn_pool(const float* __restrict__ v1, const float* __restrict__ m1,
                 const float* __restrict__ v2, const float* __restrict__ m2,
                 const float* __restrict__ rmax_p, const float* __restrict__ cmax_p,
                 float* __restrict__ pout)
{
    // XCD swizzle: 768 blocks -> 96/XCD -> consecutive batches per XCD
    const int lin = (int)blockIdx.x;
    const int swz = (lin & 7) * 96 + (lin >> 3);
    const int b = swz / 6, rem = swz % 6, side = rem / 3, chunk = rem % 3;

    const float* v  = side ? v2 : v1;
    const float* mk = side ? m2 : m1;
    const float* P  = side ? cmax_p : rmax_p;
    const int t = threadIdx.x, lane = t & 63, w = t >> 6;

    __shared__ float attn[L_];
    __shared__ float sred[4];
    __shared__ int scnt[4];

    float mkv = mk[b * L_ + t];
    float mxv = fmaxf(P[((size_t)b * 2 + 0) * L_ + t],
                      P[((size_t)b * 2 + 1) * L_ + t]);
    float s = (mkv > 0.f) ? (-mxv * 0.01f) : NEGV;

    unsigned long long bm = __ballot(mkv > 0.f);
    if (lane == 0) scnt[w] = (int)__popcll(bm);

    float wm = wred_max(s);
    if (lane == 0) sred[w] = wm;
    __syncthreads();
    float mx = fmaxf(fmaxf(sred[0], sred[1]), fmaxf(sred[2], sred[3]));
    int nlen = scnt[0] + scnt[1] + scnt[2] + scnt[3];   // prefix mask -> count
    float e = expf(s - mx);
    __syncthreads();
    float ws = wred_sum(e);
    if (lane == 0) sred[w] = ws;
    __syncthreads();
    float sum = sred[0] + sred[1] + sred[2] + sred[3];
    attn[t] = e / sum;
    __syncthreads();

    // rows >= nlen have attn == 0 exactly (expf underflow) -> skip their reads
    const int d = chunk * 256 + t;
    const float* vb = v + (size_t)b * L_ * D_ + d;
    float p = 0.f;
    #pragma unroll 8
    for (int l = 0; l < nlen; ++l) p += attn[l] * vb[(size_t)l * D_];
    pout[((size_t)b * 2 + side) * D_ + d] = p;
}

// K3: per batch: cosine similarity of p1, p2.
__global__ __launch_bounds__(256)
void k_cos(const float* __restrict__ pout, float* __restrict__ out)
{
    const int b = blockIdx.x, t = threadIdx.x, lane = t & 63, w = t >> 6;
    const float* p1 = pout + (size_t)b * 2 * D_;
    const float* p2 = p1 + D_;
    float dot = 0.f, n1 = 0.f, n2 = 0.f;
    for (int d = t; d < D_; d += 256) {
        float a = p1[d], c = p2[d];
        dot += a * c; n1 += a * a; n2 += c * c;
    }
    dot = wred_sum(dot); n1 = wred_sum(n1); n2 = wred_sum(n2);
    __shared__ float sd[4], sa[4], sc[4];
    if (lane == 0) { sd[w] = dot; sa[w] = n1; sc[w] = n2; }
    __syncthreads();
    if (t == 0) {
        float dd = sd[0] + sd[1] + sd[2] + sd[3];
        float aa = sa[0] + sa[1] + sa[2] + sa[3];
        float cc = sc[0] + sc[1] + sc[2] + sc[3];
        out[b] = dd / (fmaxf(sqrtf(aa), 1e-8f) * fmaxf(sqrtf(cc), 1e-8f));
    }
}

extern "C" void kernel_launch(void* const* d_in, const int* in_sizes, int n_in,
                              void* d_out, int out_size, void* d_ws, size_t ws_size,
                              hipStream_t stream)
{
    const float* v1 = (const float*)d_in[0];
    const float* m1 = (const float*)d_in[1];
    const float* v2 = (const float*)d_in[2];
    const float* m2 = (const float*)d_in[3];
    float* out = (float*)d_out;

    float* rmax_p = (float*)d_ws;                       // [B][2][256] row-max partials
    float* cmax_p = rmax_p + (size_t)B_ * 2 * L_;       // [B][2][256] col-max partials
    float* pout   = cmax_p + (size_t)B_ * 2 * L_;       // [B][2][768] pooled vectors

    k_match<<<dim3(4 * B_), 512, 0, stream>>>(v1, m1, v2, m2, rmax_p, cmax_p);

    k_attn_pool<<<dim3(B_ * 2 * 3), 256, 0, stream>>>(v1, m1, v2, m2, rmax_p, cmax_p, pout);

    k_cos<<<B_, 256, 0, stream>>>(pout, out);
}

// Round 17
// 70.797 us; speedup vs baseline: 2.0806x; 1.0216x over previous
//
#include <hip/hip_runtime.h>

// ParaModel_69664369541839: match = v1 @ v2^T [B,L1,L2]; masked row/col max;
// s = -max/100 masked; softmax; attention-pool p1,p2; cosine(p1,p2).
// B=128, L1=L2=256, D=768, fp32 in/out.
//
// R17 = R16 (K1 with length-skip kept frozen — best of 11 variants) + K2
// VECTORIZED (Guideline 13, overdue): pool loads were scalar 4B stride-768
// (~37.7M requests); now 4 row-groups x 64 lanes, each lane one float4
// accumulator -> 4x fewer requests, same bytes, 4 rows in flight per block.
// All session evidence says the limit is request/issue rate, not bytes.

#define B_   128
#define L_   256
#define D_   768
#define NEGV (-10000.0f)
#define NEGU 0x39E3BFFFu   // fmap(-10000.0f)

typedef _Float16 f16x8 __attribute__((ext_vector_type(8)));
typedef __fp16   h16x2 __attribute__((ext_vector_type(2)));
typedef float    f32x4 __attribute__((ext_vector_type(4)));

#define BT   128          // tile rows == cols
#define BKF  64           // fp32 k-elems per staged tile (2 MFMA K-steps)
#define NKT  (D_ / BKF)   // 12
#define LDH  72           // halves per LDS row (144B: uniform bank spread)

__device__ __forceinline__ unsigned fmap(float f) {
    unsigned u = __float_as_uint(f);
    return (u & 0x80000000u) ? ~u : (u | 0x80000000u);   // monotone float->uint
}
__device__ __forceinline__ float fdecode(unsigned u) {
    return __uint_as_float((u & 0x80000000u) ? (u ^ 0x80000000u) : ~u);
}
__device__ __forceinline__ float wred_max(float v) {
    #pragma unroll
    for (int o = 32; o; o >>= 1) v = fmaxf(v, __shfl_xor(v, o));
    return v;
}
__device__ __forceinline__ float wred_sum(float v) {
    #pragma unroll
    for (int o = 32; o; o >>= 1) v += __shfl_xor(v, o);
    return v;
}
__device__ __forceinline__ f16x8 cvt8(float4 a, float4 b) {
    union { h16x2 h2[4]; f16x8 h8; } u;
    u.h2[0] = __builtin_amdgcn_cvt_pkrtz(a.x, a.y);
    u.h2[1] = __builtin_amdgcn_cvt_pkrtz(a.z, a.w);
    u.h2[2] = __builtin_amdgcn_cvt_pkrtz(b.x, b.y);
    u.h2[3] = __builtin_amdgcn_cvt_pkrtz(b.z, b.w);
    return u.h8;
}

// K1: per (b, ti, tj): 128x128 match tile via fp16 MFMA (8 waves of 32x64).
// Length-skipped per R16. Row-max partial -> rmax_p; col partial -> cmax_p.
__global__ __launch_bounds__(512, 4)
void k_match(const float* __restrict__ v1, const float* __restrict__ m1,
             const float* __restrict__ v2, const float* __restrict__ m2,
             float* __restrict__ rmax_p, float* __restrict__ cmax_p)
{
    __shared__ __align__(16) _Float16 As[2][BT * LDH];   // 2 x 18.4 KB
    __shared__ __align__(16) _Float16 Bs[2][BT * LDH];   // 2 x 18.4 KB
    __shared__ unsigned rU[BT], cU[BT];
    __shared__ float m1s[BT], m2s[BT];
    __shared__ int sl1, sl2;

    // bijective XCD swizzle: 512 blocks, 64/XCD; a batch's 4 blocks on one XCD
    const int bid = blockIdx.x;
    const int wg  = (bid & 7) * 64 + (bid >> 3);
    const int b = wg >> 2, ti = (wg >> 1) & 1, tj = wg & 1;

    const int t = threadIdx.x;
    const int lane = t & 63, w = t >> 6;      // 8 waves
    const int wr = w >> 1, wc = w & 1;        // wave tile: 32 rows x 64 cols
    const int fr = lane & 15, fg = lane >> 4;

    if (t < BT) {
        rU[t] = NEGU; cU[t] = NEGU;           // skipped slots publish NEG
        m1s[t] = m1[b * L_ + ti * BT + t];
        m2s[t] = m2[b * L_ + tj * BT + t];
    }
    if (t == 0) { sl1 = 0; sl2 = 0; }
    __syncthreads();

    // block-local valid row/col counts (masks are prefix masks)
    unsigned long long b1 = __ballot(t < BT && m1s[t] > 0.f);
    unsigned long long b2 = __ballot(t < BT && m2s[t] > 0.f);
    if (lane == 0 && b1) atomicAdd(&sl1, (int)__popcll(b1));
    if (lane == 0 && b2) atomicAdd(&sl2, (int)__popcll(b2));
    __syncthreads();
    const int len1b = sl1, len2b = sl2;       // valid v1-rows / v2-rows in tile

    f32x4 acc[2][4] = {};

    if (len1b > 0 && len2b > 0) {
        const int s_r = t >> 2, s_c = (t & 3) * 16;
        const bool pA = s_r < len1b;
        const bool pB = s_r < len2b;
        const float* ga = v1 + ((size_t)b * L_ + ti * BT + s_r) * D_ + s_c;
        const float* gb = v2 + ((size_t)b * L_ + tj * BT + s_r) * D_ + s_c;

        float4 ra[4], rb[4];

        #define GLOAD(kt) do {                                                    \
            const float* A_ = ga + (kt) * BKF;                                    \
            const float* C_ = gb + (kt) * BKF;                                    \
            if (pA) {                                                             \
                ra[0] = *(const float4*)(A_);      ra[1] = *(const float4*)(A_ + 4);  \
                ra[2] = *(const float4*)(A_ + 8);  ra[3] = *(const float4*)(A_ + 12); \
            }                                                                     \
            if (pB) {                                                             \
                rb[0] = *(const float4*)(C_);      rb[1] = *(const float4*)(C_ + 4);  \
                rb[2] = *(const float4*)(C_ + 8);  rb[3] = *(const float4*)(C_ + 12); \
            }                                                                     \
        } while (0)

        #define DSWRITE(buf) do {                                                 \
            if (pA) {                                                             \
                _Float16* da = &As[buf][s_r * LDH + s_c];                         \
                *(f16x8*)da       = cvt8(ra[0], ra[1]);                           \
                *(f16x8*)(da + 8) = cvt8(ra[2], ra[3]);                           \
            }                                                                     \
            if (pB) {                                                             \
                _Float16* db = &Bs[buf][s_r * LDH + s_c];                         \
                *(f16x8*)db       = cvt8(rb[0], rb[1]);                           \
                *(f16x8*)(db + 8) = cvt8(rb[2], rb[3]);                           \
            }                                                                     \
        } while (0)

        const bool vi0 = (wr * 32      ) < len1b;
        const bool vi1 = (wr * 32 + 16 ) < len1b;
        const bool vj0 = (wc * 64      ) < len2b;
        const bool vj1 = (wc * 64 + 16 ) < len2b;
        const bool vj2 = (wc * 64 + 32 ) < len2b;
        const bool vj3 = (wc * 64 + 48 ) < len2b;

        GLOAD(0);
        DSWRITE(0);
        __syncthreads();
        int cur = 0;
        for (int kt = 0; kt < NKT; ++kt) {
            if (kt + 1 < NKT) GLOAD(kt + 1);      // issue next tile's loads early
            __builtin_amdgcn_sched_barrier(0);    // pin issue above the MFMA phase
            #pragma unroll
            for (int ks = 0; ks < 2; ++ks) {
                f16x8 af[2], bf[4];
                if (vi0) af[0] = *(const f16x8*)&As[cur][(wr * 32      + fr) * LDH + ks * 32 + fg * 8];
                if (vi1) af[1] = *(const f16x8*)&As[cur][(wr * 32 + 16 + fr) * LDH + ks * 32 + fg * 8];
                if (vj0) bf[0] = *(const f16x8*)&Bs[cur][(wc * 64      + fr) * LDH + ks * 32 + fg * 8];
                if (vj1) bf[1] = *(const f16x8*)&Bs[cur][(wc * 64 + 16 + fr) * LDH + ks * 32 + fg * 8];
                if (vj2) bf[2] = *(const f16x8*)&Bs[cur][(wc * 64 + 32 + fr) * LDH + ks * 32 + fg * 8];
                if (vj3) bf[3] = *(const f16x8*)&Bs[cur][(wc * 64 + 48 + fr) * LDH + ks * 32 + fg * 8];
                if (vi0) {
                    if (vj0) acc[0][0] = __builtin_amdgcn_mfma_f32_16x16x32_f16(af[0], bf[0], acc[0][0], 0, 0, 0);
                    if (vj1) acc[0][1] = __builtin_amdgcn_mfma_f32_16x16x32_f16(af[0], bf[1], acc[0][1], 0, 0, 0);
                    if (vj2) acc[0][2] = __builtin_amdgcn_mfma_f32_16x16x32_f16(af[0], bf[2], acc[0][2], 0, 0, 0);
                    if (vj3) acc[0][3] = __builtin_amdgcn_mfma_f32_16x16x32_f16(af[0], bf[3], acc[0][3], 0, 0, 0);
                }
                if (vi1) {
                    if (vj0) acc[1][0] = __builtin_amdgcn_mfma_f32_16x16x32_f16(af[1], bf[0], acc[1][0], 0, 0, 0);
                    if (vj1) acc[1][1] = __builtin_amdgcn_mfma_f32_16x16x32_f16(af[1], bf[1], acc[1][1], 0, 0, 0);
                    if (vj2) acc[1][2] = __builtin_amdgcn_mfma_f32_16x16x32_f16(af[1], bf[2], acc[1][2], 0, 0, 0);
                    if (vj3) acc[1][3] = __builtin_amdgcn_mfma_f32_16x16x32_f16(af[1], bf[3], acc[1][3], 0, 0, 0);
                }
            }
            __builtin_amdgcn_sched_barrier(0);    // cvt/ds_write stay after MFMAs
            if (kt + 1 < NKT) DSWRITE(cur ^ 1);
            __syncthreads();
            cur ^= 1;
        }
        #undef GLOAD
        #undef DSWRITE
    }

    // masked row/col max (C/D: row = wr*32 + i*16 + fg*4 + r, col = wc*64 + j*16 + fr)
    #pragma unroll
    for (int i = 0; i < 2; ++i)
        #pragma unroll
        for (int r = 0; r < 4; ++r) {
            int row = wr * 32 + i * 16 + fg * 4 + r;
            bool rv = m1s[row] > 0.f;
            float mx = NEGV;
            #pragma unroll
            for (int j = 0; j < 4; ++j) {
                int col = wc * 64 + j * 16 + fr;
                float vv = (rv && m2s[col] > 0.f) ? acc[i][j][r] : NEGV;
                mx = fmaxf(mx, vv);
            }
            atomicMax(&rU[row], fmap(mx));    // LDS-local only
        }
    #pragma unroll
    for (int j = 0; j < 4; ++j) {
        int col = wc * 64 + j * 16 + fr;
        bool cv = m2s[col] > 0.f;
        float mx = NEGV;
        #pragma unroll
        for (int i = 0; i < 2; ++i)
            #pragma unroll
            for (int r = 0; r < 4; ++r) {
                int row = wr * 32 + i * 16 + fg * 4 + r;
                float vv = (cv && m1s[row] > 0.f) ? acc[i][j][r] : NEGV;
                mx = fmaxf(mx, vv);
            }
        atomicMax(&cU[col], fmap(mx));        // LDS-local only
    }
    __syncthreads();

    if (t < BT)
        rmax_p[((size_t)b * 2 + tj) * L_ + ti * BT + t] = fdecode(rU[t]);
    else if (t < 2 * BT)
        cmax_p[((size_t)b * 2 + ti) * L_ + tj * BT + (t - BT)] = fdecode(cU[t - BT]);
}

// K2: per (b, side, chunk): combine partials -> softmax (redundant per chunk,
// cheap) -> VECTORIZED pool: 4 row-groups x 64 lanes, float4 per lane.
__global__ __launch_bounds__(256)
void k_attn_pool(const float* __restrict__ v1, const float* __restrict__ m1,
                 const float* __restrict__ v2, const float* __restrict__ m2,
                 const float* __restrict__ rmax_p, const float* __restrict__ cmax_p,
                 float* __restrict__ pout)
{
    // XCD swizzle: 768 blocks -> 96/XCD -> consecutive batches per XCD
    const int lin = (int)blockIdx.x;
    const int swz = (lin & 7) * 96 + (lin >> 3);
    const int b = swz / 6, rem = swz % 6, side = rem / 3, chunk = rem % 3;

    const float* v  = side ? v2 : v1;
    const float* mk = side ? m2 : m1;
    const float* P  = side ? cmax_p : rmax_p;
    const int t = threadIdx.x, lane = t & 63, w = t >> 6;

    __shared__ float attn[L_];
    __shared__ float sred[4];
    __shared__ int scnt[4];
    __shared__ __align__(16) float4 pbuf[4][64];   // 4 KB group partials

    float mkv = mk[b * L_ + t];
    float mxv = fmaxf(P[((size_t)b * 2 + 0) * L_ + t],
                      P[((size_t)b * 2 + 1) * L_ + t]);
    float s = (mkv > 0.f) ? (-mxv * 0.01f) : NEGV;

    unsigned long long bm = __ballot(mkv > 0.f);
    if (lane == 0) scnt[w] = (int)__popcll(bm);

    float wm = wred_max(s);
    if (lane == 0) sred[w] = wm;
    __syncthreads();
    float mx = fmaxf(fmaxf(sred[0], sred[1]), fmaxf(sred[2], sred[3]));
    int nlen = scnt[0] + scnt[1] + scnt[2] + scnt[3];   // prefix mask -> count
    float e = expf(s - mx);
    __syncthreads();
    float ws = wred_sum(e);
    if (lane == 0) sred[w] = ws;
    __syncthreads();
    float sum = sred[0] + sred[1] + sred[2] + sred[3];
    attn[t] = e / sum;
    __syncthreads();

    // pool: lane owns dims [chunk*256 + 4*lane, +4); group w strides rows.
    // rows >= nlen have attn == 0 exactly (expf underflow) -> bounded loop.
    const float* vb = v + (size_t)b * L_ * D_ + chunk * 256 + lane * 4;
    float4 p = {0.f, 0.f, 0.f, 0.f};
    #pragma unroll 4
    for (int l = w; l < nlen; l += 4) {
        float a = attn[l];
        float4 x = *(const float4*)(vb + (size_t)l * D_);
        p.x += a * x.x; p.y += a * x.y; p.z += a * x.z; p.w += a * x.w;
    }
    pbuf[w][lane] = p;
    __syncthreads();
    if (w == 0) {
        float4 q0 = pbuf[0][lane], q1 = pbuf[1][lane];
        float4 q2 = pbuf[2][lane], q3 = pbuf[3][lane];
        float4 q = { q0.x + q1.x + q2.x + q3.x,
                     q0.y + q1.y + q2.y + q3.y,
                     q0.z + q1.z + q2.z + q3.z,
                     q0.w + q1.w + q2.w + q3.w };
        *(float4*)(pout + ((size_t)b * 2 + side) * D_ + chunk * 256 + lane * 4) = q;
    }
}

// K3: per batch: cosine similarity of p1, p2.
__global__ __launch_bounds__(256)
void k_cos(const float* __restrict__ pout, float* __restrict__ out)
{
    const int b = blockIdx.x, t = threadIdx.x, lane = t & 63, w = t >> 6;
    const float* p1 = pout + (size_t)b * 2 * D_;
    const float* p2 = p1 + D_;
    float dot = 0.f, n1 = 0.f, n2 = 0.f;
    for (int d = t; d < D_; d += 256) {
        float a = p1[d], c = p2[d];
        dot += a * c; n1 += a * a; n2 += c * c;
    }
    dot = wred_sum(dot); n1 = wred_sum(n1); n2 = wred_sum(n2);
    __shared__ float sd[4], sa[4], sc[4];
    if (lane == 0) { sd[w] = dot; sa[w] = n1; sc[w] = n2; }
    __syncthreads();
    if (t == 0) {
        float dd = sd[0] + sd[1] + sd[2] + sd[3];
        float aa = sa[0] + sa[1] + sa[2] + sa[3];
        float cc = sc[0] + sc[1] + sc[2] + sc[3];
        out[b] = dd / (fmaxf(sqrtf(aa), 1e-8f) * fmaxf(sqrtf(cc), 1e-8f));
    }
}

extern "C" void kernel_launch(void* const* d_in, const int* in_sizes, int n_in,
                              void* d_out, int out_size, void* d_ws, size_t ws_size,
                              hipStream_t stream)
{
    const float* v1 = (const float*)d_in[0];
    const float* m1 = (const float*)d_in[1];
    const float* v2 = (const float*)d_in[2];
    const float* m2 = (const float*)d_in[3];
    float* out = (float*)d_out;

    float* rmax_p = (float*)d_ws;                       // [B][2][256] row-max partials
    float* cmax_p = rmax_p + (size_t)B_ * 2 * L_;       // [B][2][256] col-max partials
    float* pout   = cmax_p + (size_t)B_ * 2 * L_;       // [B][2][768] pooled vectors

    k_match<<<dim3(4 * B_), 512, 0, stream>>>(v1, m1, v2, m2, rmax_p, cmax_p);

    k_attn_pool<<<dim3(B_ * 2 * 3), 256, 0, stream>>>(v1, m1, v2, m2, rmax_p, cmax_p, pout);

    k_cos<<<B_, 256, 0, stream>>>(pout, out);
}

// Round 18
// 70.041 us; speedup vs baseline: 2.1031x; 1.0108x over previous
//
#include <hip/hip_runtime.h>

// ParaModel_69664369541839: match = v1 @ v2^T [B,L1,L2]; masked row/col max;
// s = -max/100 masked; softmax; attention-pool p1,p2; cosine(p1,p2).
// B=128, L1=L2=256, D=768, fp32 in/out.
//
// R18 = R17 with K2/K3 restructured: K2 grid (b,chunk) = 384 blocks x 512 thr,
// BOTH sides per block (softmax per half, vectorized pool per side), then the
// block computes its chunk's PARTIAL cosine sums (dot/n1/n2) locally and
// stores 3 floats -> gpart[b][chunk]. pout (768KB write + 768KB K3 read)
// eliminated; K3 = 1 block x 128 threads reading 4.6KB. K1 frozen (best of
// 11 variants, length-skipped).

#define B_   128
#define L_   256
#define D_   768
#define NEGV (-10000.0f)
#define NEGU 0x39E3BFFFu   // fmap(-10000.0f)

typedef _Float16 f16x8 __attribute__((ext_vector_type(8)));
typedef __fp16   h16x2 __attribute__((ext_vector_type(2)));
typedef float    f32x4 __attribute__((ext_vector_type(4)));

#define BT   128          // tile rows == cols
#define BKF  64           // fp32 k-elems per staged tile (2 MFMA K-steps)
#define NKT  (D_ / BKF)   // 12
#define LDH  72           // halves per LDS row (144B: uniform bank spread)

__device__ __forceinline__ unsigned fmap(float f) {
    unsigned u = __float_as_uint(f);
    return (u & 0x80000000u) ? ~u : (u | 0x80000000u);   // monotone float->uint
}
__device__ __forceinline__ float fdecode(unsigned u) {
    return __uint_as_float((u & 0x80000000u) ? (u ^ 0x80000000u) : ~u);
}
__device__ __forceinline__ float wred_max(float v) {
    #pragma unroll
    for (int o = 32; o; o >>= 1) v = fmaxf(v, __shfl_xor(v, o));
    return v;
}
__device__ __forceinline__ float wred_sum(float v) {
    #pragma unroll
    for (int o = 32; o; o >>= 1) v += __shfl_xor(v, o);
    return v;
}
__device__ __forceinline__ f16x8 cvt8(float4 a, float4 b) {
    union { h16x2 h2[4]; f16x8 h8; } u;
    u.h2[0] = __builtin_amdgcn_cvt_pkrtz(a.x, a.y);
    u.h2[1] = __builtin_amdgcn_cvt_pkrtz(a.z, a.w);
    u.h2[2] = __builtin_amdgcn_cvt_pkrtz(b.x, b.y);
    u.h2[3] = __builtin_amdgcn_cvt_pkrtz(b.z, b.w);
    return u.h8;
}

// K1: per (b, ti, tj): 128x128 match tile via fp16 MFMA (8 waves of 32x64).
// Length-skipped per R16. Row-max partial -> rmax_p; col partial -> cmax_p.
__global__ __launch_bounds__(512, 4)
void k_match(const float* __restrict__ v1, const float* __restrict__ m1,
             const float* __restrict__ v2, const float* __restrict__ m2,
             float* __restrict__ rmax_p, float* __restrict__ cmax_p)
{
    __shared__ __align__(16) _Float16 As[2][BT * LDH];   // 2 x 18.4 KB
    __shared__ __align__(16) _Float16 Bs[2][BT * LDH];   // 2 x 18.4 KB
    __shared__ unsigned rU[BT], cU[BT];
    __shared__ float m1s[BT], m2s[BT];
    __shared__ int sl1, sl2;

    // bijective XCD swizzle: 512 blocks, 64/XCD; a batch's 4 blocks on one XCD
    const int bid = blockIdx.x;
    const int wg  = (bid & 7) * 64 + (bid >> 3);
    const int b = wg >> 2, ti = (wg >> 1) & 1, tj = wg & 1;

    const int t = threadIdx.x;
    const int lane = t & 63, w = t >> 6;      // 8 waves
    const int wr = w >> 1, wc = w & 1;        // wave tile: 32 rows x 64 cols
    const int fr = lane & 15, fg = lane >> 4;

    if (t < BT) {
        rU[t] = NEGU; cU[t] = NEGU;           // skipped slots publish NEG
        m1s[t] = m1[b * L_ + ti * BT + t];
        m2s[t] = m2[b * L_ + tj * BT + t];
    }
    if (t == 0) { sl1 = 0; sl2 = 0; }
    __syncthreads();

    // block-local valid row/col counts (masks are prefix masks)
    unsigned long long b1 = __ballot(t < BT && m1s[t] > 0.f);
    unsigned long long b2 = __ballot(t < BT && m2s[t] > 0.f);
    if (lane == 0 && b1) atomicAdd(&sl1, (int)__popcll(b1));
    if (lane == 0 && b2) atomicAdd(&sl2, (int)__popcll(b2));
    __syncthreads();
    const int len1b = sl1, len2b = sl2;       // valid v1-rows / v2-rows in tile

    f32x4 acc[2][4] = {};

    if (len1b > 0 && len2b > 0) {
        const int s_r = t >> 2, s_c = (t & 3) * 16;
        const bool pA = s_r < len1b;
        const bool pB = s_r < len2b;
        const float* ga = v1 + ((size_t)b * L_ + ti * BT + s_r) * D_ + s_c;
        const float* gb = v2 + ((size_t)b * L_ + tj * BT + s_r) * D_ + s_c;

        float4 ra[4], rb[4];

        #define GLOAD(kt) do {                                                    \
            const float* A_ = ga + (kt) * BKF;                                    \
            const float* C_ = gb + (kt) * BKF;                                    \
            if (pA) {                                                             \
                ra[0] = *(const float4*)(A_);      ra[1] = *(const float4*)(A_ + 4);  \
                ra[2] = *(const float4*)(A_ + 8);  ra[3] = *(const float4*)(A_ + 12); \
            }                                                                     \
            if (pB) {                                                             \
                rb[0] = *(const float4*)(C_);      rb[1] = *(const float4*)(C_ + 4);  \
                rb[2] = *(const float4*)(C_ + 8);  rb[3] = *(const float4*)(C_ + 12); \
            }                                                                     \
        } while (0)

        #define DSWRITE(buf) do {                                                 \
            if (pA) {                                                             \
                _Float16* da = &As[buf][s_r * LDH + s_c];                         \
                *(f16x8*)da       = cvt8(ra[0], ra[1]);                           \
                *(f16x8*)(da + 8) = cvt8(ra[2], ra[3]);                           \
            }                                                                     \
            if (pB) {                                                             \
                _Float16* db = &Bs[buf][s_r * LDH + s_c];                         \
                *(f16x8*)db       = cvt8(rb[0], rb[1]);                           \
                *(f16x8*)(db + 8) = cvt8(rb[2], rb[3]);                           \
            }                                                                     \
        } while (0)

        const bool vi0 = (wr * 32      ) < len1b;
        const bool vi1 = (wr * 32 + 16 ) < len1b;
        const bool vj0 = (wc * 64      ) < len2b;
        const bool vj1 = (wc * 64 + 16 ) < len2b;
        const bool vj2 = (wc * 64 + 32 ) < len2b;
        const bool vj3 = (wc * 64 + 48 ) < len2b;

        GLOAD(0);
        DSWRITE(0);
        __syncthreads();
        int cur = 0;
        for (int kt = 0; kt < NKT; ++kt) {
            if (kt + 1 < NKT) GLOAD(kt + 1);      // issue next tile's loads early
            __builtin_amdgcn_sched_barrier(0);    // pin issue above the MFMA phase
            #pragma unroll
            for (int ks = 0; ks < 2; ++ks) {
                f16x8 af[2], bf[4];
                if (vi0) af[0] = *(const f16x8*)&As[cur][(wr * 32      + fr) * LDH + ks * 32 + fg * 8];
                if (vi1) af[1] = *(const f16x8*)&As[cur][(wr * 32 + 16 + fr) * LDH + ks * 32 + fg * 8];
                if (vj0) bf[0] = *(const f16x8*)&Bs[cur][(wc * 64      + fr) * LDH + ks * 32 + fg * 8];
                if (vj1) bf[1] = *(const f16x8*)&Bs[cur][(wc * 64 + 16 + fr) * LDH + ks * 32 + fg * 8];
                if (vj2) bf[2] = *(const f16x8*)&Bs[cur][(wc * 64 + 32 + fr) * LDH + ks * 32 + fg * 8];
                if (vj3) bf[3] = *(const f16x8*)&Bs[cur][(wc * 64 + 48 + fr) * LDH + ks * 32 + fg * 8];
                if (vi0) {
                    if (vj0) acc[0][0] = __builtin_amdgcn_mfma_f32_16x16x32_f16(af[0], bf[0], acc[0][0], 0, 0, 0);
                    if (vj1) acc[0][1] = __builtin_amdgcn_mfma_f32_16x16x32_f16(af[0], bf[1], acc[0][1], 0, 0, 0);
                    if (vj2) acc[0][2] = __builtin_amdgcn_mfma_f32_16x16x32_f16(af[0], bf[2], acc[0][2], 0, 0, 0);
                    if (vj3) acc[0][3] = __builtin_amdgcn_mfma_f32_16x16x32_f16(af[0], bf[3], acc[0][3], 0, 0, 0);
                }
                if (vi1) {
                    if (vj0) acc[1][0] = __builtin_amdgcn_mfma_f32_16x16x32_f16(af[1], bf[0], acc[1][0], 0, 0, 0);
                    if (vj1) acc[1][1] = __builtin_amdgcn_mfma_f32_16x16x32_f16(af[1], bf[1], acc[1][1], 0, 0, 0);
                    if (vj2) acc[1][2] = __builtin_amdgcn_mfma_f32_16x16x32_f16(af[1], bf[2], acc[1][2], 0, 0, 0);
                    if (vj3) acc[1][3] = __builtin_amdgcn_mfma_f32_16x16x32_f16(af[1], bf[3], acc[1][3], 0, 0, 0);
                }
            }
            __builtin_amdgcn_sched_barrier(0);    // cvt/ds_write stay after MFMAs
            if (kt + 1 < NKT) DSWRITE(cur ^ 1);
            __syncthreads();
            cur ^= 1;
        }
        #undef GLOAD
        #undef DSWRITE
    }

    // masked row/col max (C/D: row = wr*32 + i*16 + fg*4 + r, col = wc*64 + j*16 + fr)
    #pragma unroll
    for (int i = 0; i < 2; ++i)
        #pragma unroll
        for (int r = 0; r < 4; ++r) {
            int row = wr * 32 + i * 16 + fg * 4 + r;
            bool rv = m1s[row] > 0.f;
            float mx = NEGV;
            #pragma unroll
            for (int j = 0; j < 4; ++j) {
                int col = wc * 64 + j * 16 + fr;
                float vv = (rv && m2s[col] > 0.f) ? acc[i][j][r] : NEGV;
                mx = fmaxf(mx, vv);
            }
            atomicMax(&rU[row], fmap(mx));    // LDS-local only
        }
    #pragma unroll
    for (int j = 0; j < 4; ++j) {
        int col = wc * 64 + j * 16 + fr;
        bool cv = m2s[col] > 0.f;
        float mx = NEGV;
        #pragma unroll
        for (int i = 0; i < 2; ++i)
            #pragma unroll
            for (int r = 0; r < 4; ++r) {
                int row = wr * 32 + i * 16 + fg * 4 + r;
                float vv = (cv && m1s[row] > 0.f) ? acc[i][j][r] : NEGV;
                mx = fmaxf(mx, vv);
            }
        atomicMax(&cU[col], fmap(mx));        // LDS-local only
    }
    __syncthreads();

    if (t < BT)
        rmax_p[((size_t)b * 2 + tj) * L_ + ti * BT + t] = fdecode(rU[t]);
    else if (t < 2 * BT)
        cmax_p[((size_t)b * 2 + ti) * L_ + tj * BT + (t - BT)] = fdecode(cU[t - BT]);
}

// K2: per (b, chunk): both sides. Softmax per 256-thread half, vectorized pool
// (4 row-groups x 64 lanes x float4 per side), then partial cosine sums over
// this chunk's 256 dims -> gpart[b][chunk] (3 floats). No pout.
__global__ __launch_bounds__(512)
void k_attn_pool(const float* __restrict__ v1, const float* __restrict__ m1,
                 const float* __restrict__ v2, const float* __restrict__ m2,
                 const float* __restrict__ rmax_p, const float* __restrict__ cmax_p,
                 float* __restrict__ gpart)
{
    // XCD swizzle: 384 blocks -> 48/XCD -> consecutive batches per XCD
    const int lin = (int)blockIdx.x;
    const int swz = (lin & 7) * 48 + (lin >> 3);
    const int b = swz / 3, chunk = swz % 3;

    const int t = threadIdx.x, lane = t & 63, w = t >> 6;  // 8 waves
    const int h = t >> 8, l = t & 255;                     // side, row index
    const int w4 = w & 3;                                  // row-group in side

    __shared__ float attn[2][L_];
    __shared__ float sred[8];
    __shared__ int scnt[8];
    __shared__ __align__(16) float4 pbuf[2][4][64];        // 8 KB group partials
    __shared__ __align__(16) float4 pq[2][64];             // pooled chunk (both sides)

    const float* mk = h ? m2 : m1;
    const float* P  = h ? cmax_p : rmax_p;

    float mkv = mk[b * L_ + l];
    float mxv = fmaxf(P[((size_t)b * 2 + 0) * L_ + l],
                      P[((size_t)b * 2 + 1) * L_ + l]);
    float s = (mkv > 0.f) ? (-mxv * 0.01f) : NEGV;

    unsigned long long bm = __ballot(mkv > 0.f);
    if (lane == 0) scnt[w] = (int)__popcll(bm);

    float wm = wred_max(s);
    if (lane == 0) sred[w] = wm;
    __syncthreads();
    float mx = fmaxf(fmaxf(sred[h * 4 + 0], sred[h * 4 + 1]),
                     fmaxf(sred[h * 4 + 2], sred[h * 4 + 3]));
    int nlen = scnt[h * 4 + 0] + scnt[h * 4 + 1] + scnt[h * 4 + 2] + scnt[h * 4 + 3];
    float e = expf(s - mx);
    __syncthreads();
    float ws = wred_sum(e);
    if (lane == 0) sred[w] = ws;
    __syncthreads();
    float sum = sred[h * 4 + 0] + sred[h * 4 + 1] + sred[h * 4 + 2] + sred[h * 4 + 3];
    attn[h][l] = e / sum;
    __syncthreads();

    // pool: lane owns dims [chunk*256 + 4*lane, +4) of side h; group w4 strides rows.
    // rows >= nlen have attn == 0 exactly (expf underflow) -> bounded loop.
    const float* vb = (h ? v2 : v1) + (size_t)b * L_ * D_ + chunk * 256 + lane * 4;
    float4 p = {0.f, 0.f, 0.f, 0.f};
    #pragma unroll 4
    for (int ll = w4; ll < nlen; ll += 4) {
        float a = attn[h][ll];
        float4 x = *(const float4*)(vb + (size_t)ll * D_);
        p.x += a * x.x; p.y += a * x.y; p.z += a * x.z; p.w += a * x.w;
    }
    pbuf[h][w4][lane] = p;
    __syncthreads();
    if (w4 == 0) {                             // waves 0 (side 0) and 4 (side 1)
        float4 q0 = pbuf[h][0][lane], q1 = pbuf[h][1][lane];
        float4 q2 = pbuf[h][2][lane], q3 = pbuf[h][3][lane];
        float4 q = { q0.x + q1.x + q2.x + q3.x,
                     q0.y + q1.y + q2.y + q3.y,
                     q0.z + q1.z + q2.z + q3.z,
                     q0.w + q1.w + q2.w + q3.w };
        pq[h][lane] = q;
    }
    __syncthreads();

    // partial cosine sums over this chunk's 256 dims (one wave)
    if (t < 64) {
        float4 a = pq[0][lane], c = pq[1][lane];
        float dot = a.x * c.x + a.y * c.y + a.z * c.z + a.w * c.w;
        float n1  = a.x * a.x + a.y * a.y + a.z * a.z + a.w * a.w;
        float n2  = c.x * c.x + c.y * c.y + c.z * c.z + c.w * c.w;
        dot = wred_sum(dot); n1 = wred_sum(n1); n2 = wred_sum(n2);
        if (lane == 0) {
            float* gp = gpart + ((size_t)b * 3 + chunk) * 4;   // 16B-aligned slot
            gp[0] = dot; gp[1] = n1; gp[2] = n2;
        }
    }
}

// K3: 1 block x 128 threads; thread b combines 3 chunk-partials -> out[b].
__global__ __launch_bounds__(128)
void k_cos(const float* __restrict__ gpart, float* __restrict__ out)
{
    const int b = threadIdx.x;
    const float* g = gpart + (size_t)b * 12;
    float dd = g[0] + g[4] + g[8];
    float aa = g[1] + g[5] + g[9];
    float cc = g[2] + g[6] + g[10];
    out[b] = dd / (fmaxf(sqrtf(aa), 1e-8f) * fmaxf(sqrtf(cc), 1e-8f));
}

extern "C" void kernel_launch(void* const* d_in, const int* in_sizes, int n_in,
                              void* d_out, int out_size, void* d_ws, size_t ws_size,
                              hipStream_t stream)
{
    const float* v1 = (const float*)d_in[0];
    const float* m1 = (const float*)d_in[1];
    const float* v2 = (const float*)d_in[2];
    const float* m2 = (const float*)d_in[3];
    float* out = (float*)d_out;

    float* rmax_p = (float*)d_ws;                       // [B][2][256] row-max partials
    float* cmax_p = rmax_p + (size_t)B_ * 2 * L_;       // [B][2][256] col-max partials
    float* gpart  = cmax_p + (size_t)B_ * 2 * L_;       // [B][3][4] cosine partials

    k_match<<<dim3(4 * B_), 512, 0, stream>>>(v1, m1, v2, m2, rmax_p, cmax_p);

    k_attn_pool<<<dim3(B_ * 3), 512, 0, stream>>>(v1, m1, v2, m2, rmax_p, cmax_p, gpart);

    k_cos<<<dim3(1), 128, 0, stream>>>(gpart, out);
}